// Round 26
// baseline (180.753 us; speedup 1.0000x reference)
//
#include <hip/hip_runtime.h>
#include <math.h>

typedef __attribute__((ext_vector_type(4))) float f32x4;
typedef __attribute__((ext_vector_type(8))) short short8;

__device__ __forceinline__ unsigned short f2bf(float f) {
    union { float f; unsigned u; } v; v.f = f;
    unsigned r = v.u + 0x7FFFu + ((v.u >> 16) & 1u);
    return (unsigned short)(r >> 16);
}
__device__ __forceinline__ unsigned short f2bf_trunc(float f) {
    union { float f; unsigned u; } v; v.f = f;
    return (unsigned short)(v.u >> 16);
}
__device__ __forceinline__ float bf2f(unsigned short h) {
    union { unsigned u; float f; } v; v.u = ((unsigned)h) << 16;
    return v.f;
}

__device__ __forceinline__ f32x4 mfma_bf16(short8 a, short8 b, f32x4 c) {
    return __builtin_amdgcn_mfma_f32_16x16x32_bf16(a, b, c, 0, 0, 0);
}

// direct HBM->LDS DMA, 16B per lane, no VGPR round-trip
__device__ __forceinline__ void gload_lds16(const unsigned short* g, unsigned short* l) {
    __builtin_amdgcn_global_load_lds(
        (const __attribute__((address_space(1))) void*)g,
        (__attribute__((address_space(3))) void*)l, 16, 0, 0);
}

// ---------------------------------------------------------------------------
// Merged split: fp32 -> (bf16 hi, lo) for BOTH x and W in one launch
// ---------------------------------------------------------------------------
__global__ void split_all(const float* __restrict__ x,
                          unsigned short* __restrict__ xh, unsigned short* __restrict__ xl,
                          const float* __restrict__ Wm,
                          unsigned short* __restrict__ wh, unsigned short* __restrict__ wl,
                          int nx4, int nw4)
{
    int i = blockIdx.x * 256 + threadIdx.x;
    const float* src; unsigned short* dh; unsigned short* dl; int j;
    if (i < nx4) { src = x; dh = xh; dl = xl; j = i; }
    else if (i < nx4 + nw4) { src = Wm; dh = wh; dl = wl; j = i - nx4; }
    else return;
    float4 v = ((const float4*)src)[j];
    ushort4 h, l;
    h.x = f2bf(v.x); l.x = f2bf(v.x - bf2f(h.x));
    h.y = f2bf(v.y); l.y = f2bf(v.y - bf2f(h.y));
    h.z = f2bf(v.z); l.z = f2bf(v.z - bf2f(h.z));
    h.w = f2bf(v.w); l.w = f2bf(v.w - bf2f(h.w));
    ((ushort4*)dh)[j] = h;
    ((ushort4*)dl)[j] = l;
}

// ---------------------------------------------------------------------------
// Projection GEMM: qkvgr = x @ W^T   (M=4096, N=3088->3200, K=1024)
//  Round-21/22 structure (proven ~95us): 48KB LDS, 3 blocks/CU,
//  weight-balanced 768-block single-wave grid, lo hidden under hh-MFMAs.
// ---------------------------------------------------------------------------
__global__ __launch_bounds__(256, 3)
void gemm_proj(const unsigned short* __restrict__ xh, const unsigned short* __restrict__ xl,
               const unsigned short* __restrict__ wh, const unsigned short* __restrict__ wl,
               unsigned short* __restrict__ Qh, unsigned short* __restrict__ Ql,
               unsigned short* __restrict__ Kh, unsigned short* __restrict__ Kl,
               unsigned short* __restrict__ Vtg, float* __restrict__ gbuf)
{
    __shared__ __align__(16) unsigned short Ah[2][128][32];
    __shared__ __align__(16) unsigned short Bh[2][128][32];
    __shared__ __align__(16) unsigned short Al[128][32];
    __shared__ __align__(16) unsigned short Bl[128][32];

    const int bid = blockIdx.x;            // 768 blocks
    int nt0, mt0, nt1 = -1, mt1 = 0;
    if (bid < 544) {                       // slow tiles: nt 24, 0..15
        int snt = bid >> 5;                // 0..16
        nt0 = (snt == 0) ? 24 : snt - 1;
        mt0 = bid & 31;
    } else {
        int f = bid - 544;                 // 0..223
        if (f < 192) { nt0 = 16 + (f >> 5); mt0 = f & 31; }   // nt 16..21
        else { int ff = f - 192; nt0 = 22; mt0 = ff; nt1 = 23; mt1 = ff; }
    }
    const int npass = (nt1 >= 0) ? 2 : 1;

    const int tid = threadIdx.x;
    const int w = tid >> 6, l = tid & 63;
    const int wm = w >> 1, wn = w & 1;
    const int lr = l & 15, lq = l >> 4;
    const int xs = (lr >> 1) & 3;          // read-side swizzle selector
    const int srow = tid >> 2;             // 0..63
    const int sp = tid & 3;

    for (int pass = 0; pass < npass; ++pass) {
        const int nt = pass ? nt1 : nt0;
        const int mt = pass ? mt1 : mt0;
        const int m0 = mt * 128, n0 = nt * 128;
        const bool needLo = (nt < 16) || (nt == 24);

        f32x4 acc[4][4];
#pragma unroll
        for (int i = 0; i < 4; ++i)
#pragma unroll
            for (int j = 0; j < 4; ++j) acc[i][j] = (f32x4){0.f, 0.f, 0.f, 0.f};

        auto STAGE_HI = [&](int bsel, int k0) {
#pragma unroll
            for (int p = 0; p < 2; ++p) {
                int r = srow + p * 64;
                int sc = (sp ^ ((r >> 1) & 3)) * 8;   // inverse-swizzled source chunk
                int o = n0 + r;
                int oc = o < 3088 ? o : 3087;         // clamp OOB (values unused)
                gload_lds16(&xh[(size_t)(m0 + r) * 1024 + k0 + sc], &Ah[bsel][r][sp * 8]);
                gload_lds16(&wh[(size_t)oc * 1024 + k0 + sc],       &Bh[bsel][r][sp * 8]);
            }
        };
        auto STAGE_LO = [&](int k0) {
#pragma unroll
            for (int p = 0; p < 2; ++p) {
                int r = srow + p * 64;
                int sc = (sp ^ ((r >> 1) & 3)) * 8;
                int o = n0 + r;
                int oc = o < 3088 ? o : 3087;
                gload_lds16(&xl[(size_t)(m0 + r) * 1024 + k0 + sc], &Al[r][sp * 8]);
                gload_lds16(&wl[(size_t)oc * 1024 + k0 + sc],       &Bl[r][sp * 8]);
            }
        };

        // prologue: hi(0) only; lo(0) staged inside iter 0
        STAGE_HI(0, 0);
        __asm__ volatile("s_waitcnt vmcnt(0)" ::: "memory");
        __syncthreads();

        int cur = 0;
        for (int t = 0; t < 32; ++t) {
            const int k0 = t * 32;
            if (needLo) STAGE_LO(k0);                  // into single lo buffer
            if (t + 1 < 32) STAGE_HI(cur ^ 1, k0 + 32);

            // ---- phase A: hi fragments + hh MFMAs (hides lo stage latency) ----
            short8 ah[4], bh4[4];
#pragma unroll
            for (int i = 0; i < 4; ++i) {
                ah[i]  = *(const short8*)&Ah[cur][wm * 64 + i * 16 + lr][(lq ^ xs) * 8];
                bh4[i] = *(const short8*)&Bh[cur][wn * 64 + i * 16 + lr][(lq ^ xs) * 8];
            }
#pragma unroll
            for (int i = 0; i < 4; ++i)
#pragma unroll
                for (int j = 0; j < 4; ++j)
                    acc[i][j] = mfma_bf16(ah[i], bh4[j], acc[i][j]);

            if (needLo) {
                // lo(t) complete: counted wait (leaves hi(t+1) in flight), then
                // barrier for cross-wave visibility of the lo LDS writes.
                if (t + 1 < 32) {
                    __asm__ volatile("s_waitcnt vmcnt(4)" ::: "memory");
                } else {
                    __asm__ volatile("s_waitcnt vmcnt(0)" ::: "memory");
                }
                __syncthreads();

                short8 al4[4], bl4[4];
#pragma unroll
                for (int i = 0; i < 4; ++i) {
                    al4[i] = *(const short8*)&Al[wm * 64 + i * 16 + lr][(lq ^ xs) * 8];
                    bl4[i] = *(const short8*)&Bl[wn * 64 + i * 16 + lr][(lq ^ xs) * 8];
                }
#pragma unroll
                for (int i = 0; i < 4; ++i)
#pragma unroll
                    for (int j = 0; j < 4; ++j) {
                        acc[i][j] = mfma_bf16(ah[i], bl4[j], acc[i][j]);
                        acc[i][j] = mfma_bf16(al4[i], bh4[j], acc[i][j]);
                    }
            }

            // end of iter: hi(t+1) complete (had the whole iter) + visibility
            __asm__ volatile("s_waitcnt vmcnt(0)" ::: "memory");
            __syncthreads();
            cur ^= 1;
        }

        // epilogue (unchanged)
#pragma unroll
        for (int i = 0; i < 4; ++i) {
            int nrow0 = m0 + wm * 64 + i * 16 + lq * 4;
            int b = nrow0 >> 11;
            int tbase = nrow0 & 2047;
#pragma unroll
            for (int j = 0; j < 4; ++j) {
                int o = n0 + wn * 64 + j * 16 + lr;
                if (o < 1024) {
                    int h = o >> 6, d = o & 63;
                    size_t base = ((size_t)(b * 16 + h) * 2048 + tbase) * 64 + d;
#pragma unroll
                    for (int r = 0; r < 4; ++r) {
                        float v = acc[i][j][r];
                        unsigned short hi_ = f2bf(v);
                        unsigned short lo_ = f2bf(v - bf2f(hi_));
                        Qh[base + (size_t)r * 64] = hi_;
                        Ql[base + (size_t)r * 64] = lo_;
                    }
                } else if (o < 2048) {
                    int oo = o - 1024;
                    int h = oo >> 6, d = oo & 63;
                    size_t base = ((size_t)(b * 16 + h) * 2048 + tbase) * 64 + d;
#pragma unroll
                    for (int r = 0; r < 4; ++r) {
                        float v = acc[i][j][r];
                        unsigned short hi_ = f2bf(v);
                        unsigned short lo_ = f2bf(v - bf2f(hi_));
                        Kh[base + (size_t)r * 64] = hi_;
                        Kl[base + (size_t)r * 64] = lo_;
                    }
                } else if (o < 3072) {
                    int oo = o - 2048;
                    int h = oo >> 6, d = oo & 63;
                    size_t base = ((size_t)(b * 16 + h) * 64 + d) * 2048 + tbase;
                    ushort4 pk;
                    pk.x = f2bf(acc[i][j][0]);
                    pk.y = f2bf(acc[i][j][1]);
                    pk.z = f2bf(acc[i][j][2]);
                    pk.w = f2bf(acc[i][j][3]);
                    *(ushort4*)&Vtg[base] = pk;
                } else if (o < 3088) {
                    int og = o - 3072;
#pragma unroll
                    for (int r = 0; r < 4; ++r)
                        gbuf[(size_t)(nrow0 + r) * 16 + og] = acc[i][j][r];
                }
            }
        }

        if (pass + 1 < npass) __syncthreads();   // reuse LDS safely next pass
    }
}

// ---------------------------------------------------------------------------
// Gate scan (unchanged): logG2[bh][t] = cumsum log_sigmoid * log2(e)
// ---------------------------------------------------------------------------
__global__ void gate_scan(const float* __restrict__ g, float* __restrict__ lg)
{
    const int bh = blockIdx.x;
    const int b = bh >> 4, h = bh & 15;
    const int tid = threadIdx.x;
    __shared__ float part[256];

    float vals[8];
    float run = 0.f;
#pragma unroll
    for (int j = 0; j < 8; ++j) {
        int t = tid * 8 + j;
        float x = g[(size_t)(b * 2048 + t) * 16 + h];
        float ls = fminf(x, 0.f) - log1pf(__expf(-fabsf(x)));
        run += ls * 1.4426950408889634f;
        vals[j] = run;
    }
    part[tid] = run;
    __syncthreads();
    for (int ofs = 1; ofs < 256; ofs <<= 1) {
        float add = (tid >= ofs) ? part[tid - ofs] : 0.f;
        __syncthreads();
        part[tid] += add;
        __syncthreads();
    }
    float excl = part[tid] - run;
#pragma unroll
    for (int j = 0; j < 8; ++j)
        lg[(size_t)bh * 2048 + tid * 8 + j] = excl + vals[j];
}

// ---------------------------------------------------------------------------
// Flash-style causal gated power attention (round-25 structure) + T5
// s_setprio(1) around both MFMA clusters: independent blocks at different
// tile phases co-reside (3/CU, LPT-staggered) -> the m191 regime where the
// scheduler hint pays; zero-cost, numerics-identical.
// ---------------------------------------------------------------------------
__global__ __launch_bounds__(256, 3)
void attn_fwd(const unsigned short* __restrict__ Qh, const unsigned short* __restrict__ Ql,
              const unsigned short* __restrict__ Kh, const unsigned short* __restrict__ Kl,
              const unsigned short* __restrict__ Vtg, const float* __restrict__ lg,
              float* __restrict__ out)
{
    __shared__ __align__(16) unsigned short kh[2][64][64];
    __shared__ __align__(16) unsigned short kl[2][64][64];
    __shared__ __align__(16) unsigned short pl[4][16][64];

    const int bid = blockIdx.x;
    const int x8 = bid & 7;                 // assumed XCD id (round-robin)
    const int k  = bid >> 3;                // 0..127
    const int bh = x8 + 8 * (k & 3);        // 4 heads per XCD -> L2 affinity
    const int m  = k >> 2;                  // 0..31
    const int qi = 31 - m;                  // LPT: longest blocks dispatch first
    const int tid = threadIdx.x;
    const int w = tid >> 6, l = tid & 63;
    const int lr = l & 15, lq = l >> 4;
    const int xk = lr & 7;
    const int q0 = qi * 64;
    const int myrow0 = q0 + w * 16;

    const size_t qoff = ((size_t)bh * 2048 + myrow0 + lr) * 64;
    short8 qh8[2], ql8[2];
    qh8[0] = *(const short8*)&Qh[qoff + lq * 8];
    qh8[1] = *(const short8*)&Qh[qoff + 32 + lq * 8];
    ql8[0] = *(const short8*)&Ql[qoff + lq * 8];
    ql8[1] = *(const short8*)&Ql[qoff + 32 + lq * 8];

    float gq2[4];
#pragma unroll
    for (int r = 0; r < 4; ++r)
        gq2[r] = lg[(size_t)bh * 2048 + myrow0 + lq * 4 + r] - 3.0f;  // + log2(1/8)

    // row factors relative to row 0 (once per block; bounded [2^-25, 1])
    float er[4];
    er[0] = 1.f;
#pragma unroll
    for (int r = 1; r < 4; ++r) er[r] = exp2f(gq2[r] - gq2[0]);
    const float gq0 = gq2[0];

    f32x4 ls4 = (f32x4){0.f, 0.f, 0.f, 0.f};
    f32x4 o4[4];
#pragma unroll
    for (int i = 0; i < 4; ++i) o4[i] = (f32x4){0.f, 0.f, 0.f, 0.f};

    short8 ones8;
#pragma unroll
    for (int j = 0; j < 8; ++j) ones8[j] = (short)0x3F80;   // bf16 1.0

    const int srow = tid >> 3;          // 0..31  (+32 on 2nd pass)
    const int schunk = tid & 7;         // 16B chunk index

    const unsigned short* Kh_b = Kh + (size_t)bh * 2048 * 64;
    const unsigned short* Kl_b = Kl + (size_t)bh * 2048 * 64;
    const unsigned short* Vt_b = Vtg + (size_t)bh * 64 * 2048;

    auto STAGE = [&](int bsel, int kv0) {
#pragma unroll
        for (int p = 0; p < 2; ++p) {
            int r = srow + p * 32;
            int sc = (schunk ^ (r & 7)) * 8;     // inverse-swizzled source chunk
            gload_lds16(&Kh_b[(size_t)(kv0 + r) * 64 + sc], &kh[bsel][r][schunk * 8]);
            gload_lds16(&Kl_b[(size_t)(kv0 + r) * 64 + sc], &kl[bsel][r][schunk * 8]);
        }
    };

    STAGE(0, 0);
    __asm__ volatile("s_waitcnt vmcnt(0)" ::: "memory");
    __syncthreads();

    int cur = 0;
    for (int kv0 = 0; kv0 <= q0; kv0 += 64) {
        // V tile -> registers (issued first; L2-hot)
        uint4 vreg[8];
#pragma unroll
        for (int ds_ = 0; ds_ < 4; ++ds_) {
            const unsigned short* vp = &Vt_b[(size_t)(ds_ * 16 + lr) * 2048 + kv0 + lq * 8];
            vreg[ds_ * 2]     = *(const uint4*)vp;
            vreg[ds_ * 2 + 1] = *(const uint4*)(vp + 32);
        }
        if (kv0 + 64 <= q0) STAGE(cur ^ 1, kv0 + 64);   // overlap with compute

        // column gate factors (4 exp2/tile, replaces 16 exp2)
        float ec[4];
#pragma unroll
        for (int js = 0; js < 4; ++js)
            ec[js] = exp2f(gq0 - lg[(size_t)bh * 2048 + kv0 + js * 16 + lr]);

        // ---- S = Q K^T (split-bf16, 3 MFMA) ----
        f32x4 sa[4];
#pragma unroll
        for (int js = 0; js < 4; ++js) sa[js] = (f32x4){0.f, 0.f, 0.f, 0.f};
        __builtin_amdgcn_s_setprio(1);
#pragma unroll
        for (int js = 0; js < 4; ++js)
#pragma unroll
            for (int ks = 0; ks < 2; ++ks) {
                short8 kb  = *(const short8*)&kh[cur][js * 16 + lr][((ks * 4 + lq) ^ xk) << 3];
                short8 kbl = *(const short8*)&kl[cur][js * 16 + lr][((ks * 4 + lq) ^ xk) << 3];
                sa[js] = mfma_bf16(qh8[ks], kb,  sa[js]);
                sa[js] = mfma_bf16(qh8[ks], kbl, sa[js]);
                sa[js] = mfma_bf16(ql8[ks], kb,  sa[js]);
            }
        __builtin_amdgcn_s_setprio(0);

        // ---- linear scores w = (|S|+eps)^2 * er[r]*ec[js]; no normalization ----
        const bool diag = (kv0 == q0);
#pragma unroll
        for (int js = 0; js < 4; ++js) {
            float ecj = ec[js];
#pragma unroll
            for (int r = 0; r < 4; ++r) {
                float a = fabsf(sa[js][r]) + 1e-7f;
                float wv = a * a * (er[r] * ecj);
                if (diag && (js * 16 + lr > w * 16 + lq * 4 + r)) wv = 0.f;
                sa[js][r] = wv;
            }
        }

        // ---- P -> LDS (swizzled transpose, wave-local; truncating cast) ----
#pragma unroll
        for (int js = 0; js < 4; ++js)
#pragma unroll
            for (int r = 0; r < 4; ++r) {
                int prow = lq * 4 + r;
                int cch = (js * 2 + (lr >> 3)) ^ (prow & 7);
                pl[w][prow][(cch << 3) | (lr & 7)] = f2bf_trunc(sa[js][r]);
            }
        __asm__ volatile("s_waitcnt lgkmcnt(0)" ::: "memory");
        __builtin_amdgcn_sched_barrier(0);

        short8 pa0 = *(const short8*)&pl[w][lr][((0 + lq) ^ xk) << 3];
        short8 pa1 = *(const short8*)&pl[w][lr][((4 + lq) ^ xk) << 3];

        // row sums via ones-MFMA (every lane gets ls[r] for its rows)
        __builtin_amdgcn_s_setprio(1);
        ls4 = mfma_bf16(pa0, ones8, ls4);
        ls4 = mfma_bf16(pa1, ones8, ls4);
#pragma unroll
        for (int ds_ = 0; ds_ < 4; ++ds_) {
            short8 vb0 = *(const short8*)&vreg[ds_ * 2];
            short8 vb1 = *(const short8*)&vreg[ds_ * 2 + 1];
            o4[ds_] = mfma_bf16(pa0, vb0, o4[ds_]);
            o4[ds_] = mfma_bf16(pa1, vb1, o4[ds_]);
        }
        __builtin_amdgcn_s_setprio(0);

        __asm__ volatile("s_waitcnt vmcnt(0)" ::: "memory");
        __syncthreads();
        cur ^= 1;
    }

    const int b = bh >> 4, h = bh & 15;
#pragma unroll
    for (int ds_ = 0; ds_ < 4; ++ds_)
#pragma unroll
        for (int r = 0; r < 4; ++r) {
            int t = myrow0 + lq * 4 + r;
            out[(size_t)(b * 2048 + t) * 1024 + h * 64 + ds_ * 16 + lr] =
                o4[ds_][r] / ls4[r];
        }
}

// ---------------------------------------------------------------------------
extern "C" void kernel_launch(void* const* d_in, const int* in_sizes, int n_in,
                              void* d_out, int out_size, void* d_ws, size_t ws_size,
                              hipStream_t stream)
{
    const float* x = (const float*)d_in[0];   // [2][2048][1024]
    const float* W = (const float*)d_in[1];   // [3088][1024]
    float* out = (float*)d_out;               // [2][2048][1024]

    const size_t NX = 4194304;    // 2*2048*1024
    const size_t NW = 3162112;    // 3088*1024
    const size_t NQ = 4194304;    // 32*2048*64

    char* ws = (char*)d_ws;
    size_t off = 0;
    auto alloc = [&](size_t bytes) -> void* {
        void* p = ws + off;
        off += (bytes + 255) & ~(size_t)255;
        return p;
    };
    unsigned short* xh = (unsigned short*)alloc(NX * 2);
    unsigned short* xl = (unsigned short*)alloc(NX * 2);
    unsigned short* wh = (unsigned short*)alloc(NW * 2);
    unsigned short* wl = (unsigned short*)alloc(NW * 2);
    unsigned short* Qh = (unsigned short*)alloc(NQ * 2);
    unsigned short* Ql = (unsigned short*)alloc(NQ * 2);
    unsigned short* Kh = (unsigned short*)alloc(NQ * 2);
    unsigned short* Kl = (unsigned short*)alloc(NQ * 2);
    unsigned short* Vt = (unsigned short*)alloc(NQ * 2);
    float* g  = (float*)alloc(65536 * 4);
    float* lg = (float*)alloc(65536 * 4);
    if (off > ws_size) return;

    const int nx4 = (int)(NX / 4), nw4 = (int)(NW / 4);
    split_all<<<(nx4 + nw4 + 255) / 256, 256, 0, stream>>>(x, xh, xl, W, wh, wl, nx4, nw4);
    gemm_proj<<<768, 256, 0, stream>>>(xh, xl, wh, wl, Qh, Ql, Kh, Kl, Vt, g);
    gate_scan<<<32, 256, 0, stream>>>(g, lg);
    attn_fwd<<<1024, 256, 0, stream>>>(Qh, Ql, Kh, Kl, Vt, lg, out);
}

// Round 27
// 179.054 us; speedup vs baseline: 1.0095x; 1.0095x over previous
//
#include <hip/hip_runtime.h>
#include <math.h>

typedef __attribute__((ext_vector_type(4))) float f32x4;
typedef __attribute__((ext_vector_type(8))) short short8;

__device__ __forceinline__ unsigned short f2bf(float f) {
    union { float f; unsigned u; } v; v.f = f;
    unsigned r = v.u + 0x7FFFu + ((v.u >> 16) & 1u);
    return (unsigned short)(r >> 16);
}
__device__ __forceinline__ unsigned short f2bf_trunc(float f) {
    union { float f; unsigned u; } v; v.f = f;
    return (unsigned short)(v.u >> 16);
}
__device__ __forceinline__ float bf2f(unsigned short h) {
    union { unsigned u; float f; } v; v.u = ((unsigned)h) << 16;
    return v.f;
}

__device__ __forceinline__ f32x4 mfma_bf16(short8 a, short8 b, f32x4 c) {
    return __builtin_amdgcn_mfma_f32_16x16x32_bf16(a, b, c, 0, 0, 0);
}

// direct HBM->LDS DMA, 16B per lane, no VGPR round-trip
__device__ __forceinline__ void gload_lds16(const unsigned short* g, unsigned short* l) {
    __builtin_amdgcn_global_load_lds(
        (const __attribute__((address_space(1))) void*)g,
        (__attribute__((address_space(3))) void*)l, 16, 0, 0);
}

// ---------------------------------------------------------------------------
// Merged split: fp32 -> (bf16 hi, lo) for BOTH x and W in one launch
// ---------------------------------------------------------------------------
__global__ void split_all(const float* __restrict__ x,
                          unsigned short* __restrict__ xh, unsigned short* __restrict__ xl,
                          const float* __restrict__ Wm,
                          unsigned short* __restrict__ wh, unsigned short* __restrict__ wl,
                          int nx4, int nw4)
{
    int i = blockIdx.x * 256 + threadIdx.x;
    const float* src; unsigned short* dh; unsigned short* dl; int j;
    if (i < nx4) { src = x; dh = xh; dl = xl; j = i; }
    else if (i < nx4 + nw4) { src = Wm; dh = wh; dl = wl; j = i - nx4; }
    else return;
    float4 v = ((const float4*)src)[j];
    ushort4 h, l;
    h.x = f2bf(v.x); l.x = f2bf(v.x - bf2f(h.x));
    h.y = f2bf(v.y); l.y = f2bf(v.y - bf2f(h.y));
    h.z = f2bf(v.z); l.z = f2bf(v.z - bf2f(h.z));
    h.w = f2bf(v.w); l.w = f2bf(v.w - bf2f(h.w));
    ((ushort4*)dh)[j] = h;
    ((ushort4*)dl)[j] = l;
}

// ---------------------------------------------------------------------------
// Projection GEMM: qkvgr = x @ W^T   (M=4096, N=3088->3200, K=1024)
//  48KB LDS, 3 blocks/CU, weight-balanced 768-block single-wave grid,
//  lo staged into single buffer hidden under hh-MFMAs (counted vmcnt).
// ---------------------------------------------------------------------------
__global__ __launch_bounds__(256, 3)
void gemm_proj(const unsigned short* __restrict__ xh, const unsigned short* __restrict__ xl,
               const unsigned short* __restrict__ wh, const unsigned short* __restrict__ wl,
               unsigned short* __restrict__ Qh, unsigned short* __restrict__ Ql,
               unsigned short* __restrict__ Kh, unsigned short* __restrict__ Kl,
               unsigned short* __restrict__ Vtg, float* __restrict__ gbuf)
{
    __shared__ __align__(16) unsigned short Ah[2][128][32];
    __shared__ __align__(16) unsigned short Bh[2][128][32];
    __shared__ __align__(16) unsigned short Al[128][32];
    __shared__ __align__(16) unsigned short Bl[128][32];

    const int bid = blockIdx.x;            // 768 blocks
    int nt0, mt0, nt1 = -1, mt1 = 0;
    if (bid < 544) {                       // slow tiles: nt 24, 0..15
        int snt = bid >> 5;                // 0..16
        nt0 = (snt == 0) ? 24 : snt - 1;
        mt0 = bid & 31;
    } else {
        int f = bid - 544;                 // 0..223
        if (f < 192) { nt0 = 16 + (f >> 5); mt0 = f & 31; }   // nt 16..21
        else { int ff = f - 192; nt0 = 22; mt0 = ff; nt1 = 23; mt1 = ff; }
    }
    const int npass = (nt1 >= 0) ? 2 : 1;

    const int tid = threadIdx.x;
    const int w = tid >> 6, l = tid & 63;
    const int wm = w >> 1, wn = w & 1;
    const int lr = l & 15, lq = l >> 4;
    const int xs = (lr >> 1) & 3;          // read-side swizzle selector
    const int srow = tid >> 2;             // 0..63
    const int sp = tid & 3;

    for (int pass = 0; pass < npass; ++pass) {
        const int nt = pass ? nt1 : nt0;
        const int mt = pass ? mt1 : mt0;
        const int m0 = mt * 128, n0 = nt * 128;
        const bool needLo = (nt < 16) || (nt == 24);

        f32x4 acc[4][4];
#pragma unroll
        for (int i = 0; i < 4; ++i)
#pragma unroll
            for (int j = 0; j < 4; ++j) acc[i][j] = (f32x4){0.f, 0.f, 0.f, 0.f};

        auto STAGE_HI = [&](int bsel, int k0) {
#pragma unroll
            for (int p = 0; p < 2; ++p) {
                int r = srow + p * 64;
                int sc = (sp ^ ((r >> 1) & 3)) * 8;   // inverse-swizzled source chunk
                int o = n0 + r;
                int oc = o < 3088 ? o : 3087;         // clamp OOB (values unused)
                gload_lds16(&xh[(size_t)(m0 + r) * 1024 + k0 + sc], &Ah[bsel][r][sp * 8]);
                gload_lds16(&wh[(size_t)oc * 1024 + k0 + sc],       &Bh[bsel][r][sp * 8]);
            }
        };
        auto STAGE_LO = [&](int k0) {
#pragma unroll
            for (int p = 0; p < 2; ++p) {
                int r = srow + p * 64;
                int sc = (sp ^ ((r >> 1) & 3)) * 8;
                int o = n0 + r;
                int oc = o < 3088 ? o : 3087;
                gload_lds16(&xl[(size_t)(m0 + r) * 1024 + k0 + sc], &Al[r][sp * 8]);
                gload_lds16(&wl[(size_t)oc * 1024 + k0 + sc],       &Bl[r][sp * 8]);
            }
        };

        // prologue: hi(0) only; lo(0) staged inside iter 0
        STAGE_HI(0, 0);
        __asm__ volatile("s_waitcnt vmcnt(0)" ::: "memory");
        __syncthreads();

        int cur = 0;
        for (int t = 0; t < 32; ++t) {
            const int k0 = t * 32;
            if (needLo) STAGE_LO(k0);                  // into single lo buffer
            if (t + 1 < 32) STAGE_HI(cur ^ 1, k0 + 32);

            // ---- phase A: hi fragments + hh MFMAs (hides lo stage latency) ----
            short8 ah[4], bh4[4];
#pragma unroll
            for (int i = 0; i < 4; ++i) {
                ah[i]  = *(const short8*)&Ah[cur][wm * 64 + i * 16 + lr][(lq ^ xs) * 8];
                bh4[i] = *(const short8*)&Bh[cur][wn * 64 + i * 16 + lr][(lq ^ xs) * 8];
            }
#pragma unroll
            for (int i = 0; i < 4; ++i)
#pragma unroll
                for (int j = 0; j < 4; ++j)
                    acc[i][j] = mfma_bf16(ah[i], bh4[j], acc[i][j]);

            if (needLo) {
                // lo(t) complete: counted wait (leaves hi(t+1) in flight), then
                // barrier for cross-wave visibility of the lo LDS writes.
                if (t + 1 < 32) {
                    __asm__ volatile("s_waitcnt vmcnt(4)" ::: "memory");
                } else {
                    __asm__ volatile("s_waitcnt vmcnt(0)" ::: "memory");
                }
                __syncthreads();

                short8 al4[4], bl4[4];
#pragma unroll
                for (int i = 0; i < 4; ++i) {
                    al4[i] = *(const short8*)&Al[wm * 64 + i * 16 + lr][(lq ^ xs) * 8];
                    bl4[i] = *(const short8*)&Bl[wn * 64 + i * 16 + lr][(lq ^ xs) * 8];
                }
#pragma unroll
                for (int i = 0; i < 4; ++i)
#pragma unroll
                    for (int j = 0; j < 4; ++j) {
                        acc[i][j] = mfma_bf16(ah[i], bl4[j], acc[i][j]);
                        acc[i][j] = mfma_bf16(al4[i], bh4[j], acc[i][j]);
                    }
            }

            // end of iter: hi(t+1) complete (had the whole iter) + visibility
            __asm__ volatile("s_waitcnt vmcnt(0)" ::: "memory");
            __syncthreads();
            cur ^= 1;
        }

        // epilogue (unchanged)
#pragma unroll
        for (int i = 0; i < 4; ++i) {
            int nrow0 = m0 + wm * 64 + i * 16 + lq * 4;
            int b = nrow0 >> 11;
            int tbase = nrow0 & 2047;
#pragma unroll
            for (int j = 0; j < 4; ++j) {
                int o = n0 + wn * 64 + j * 16 + lr;
                if (o < 1024) {
                    int h = o >> 6, d = o & 63;
                    size_t base = ((size_t)(b * 16 + h) * 2048 + tbase) * 64 + d;
#pragma unroll
                    for (int r = 0; r < 4; ++r) {
                        float v = acc[i][j][r];
                        unsigned short hi_ = f2bf(v);
                        unsigned short lo_ = f2bf(v - bf2f(hi_));
                        Qh[base + (size_t)r * 64] = hi_;
                        Ql[base + (size_t)r * 64] = lo_;
                    }
                } else if (o < 2048) {
                    int oo = o - 1024;
                    int h = oo >> 6, d = oo & 63;
                    size_t base = ((size_t)(b * 16 + h) * 2048 + tbase) * 64 + d;
#pragma unroll
                    for (int r = 0; r < 4; ++r) {
                        float v = acc[i][j][r];
                        unsigned short hi_ = f2bf(v);
                        unsigned short lo_ = f2bf(v - bf2f(hi_));
                        Kh[base + (size_t)r * 64] = hi_;
                        Kl[base + (size_t)r * 64] = lo_;
                    }
                } else if (o < 3072) {
                    int oo = o - 2048;
                    int h = oo >> 6, d = oo & 63;
                    size_t base = ((size_t)(b * 16 + h) * 64 + d) * 2048 + tbase;
                    ushort4 pk;
                    pk.x = f2bf(acc[i][j][0]);
                    pk.y = f2bf(acc[i][j][1]);
                    pk.z = f2bf(acc[i][j][2]);
                    pk.w = f2bf(acc[i][j][3]);
                    *(ushort4*)&Vtg[base] = pk;
                } else if (o < 3088) {
                    int og = o - 3072;
#pragma unroll
                    for (int r = 0; r < 4; ++r)
                        gbuf[(size_t)(nrow0 + r) * 16 + og] = acc[i][j][r];
                }
            }
        }

        if (pass + 1 < npass) __syncthreads();   // reuse LDS safely next pass
    }
}

// ---------------------------------------------------------------------------
// Gate scan: logG2[bh][t] = cumsum log_sigmoid * log2(e)
// ---------------------------------------------------------------------------
__global__ void gate_scan(const float* __restrict__ g, float* __restrict__ lg)
{
    const int bh = blockIdx.x;
    const int b = bh >> 4, h = bh & 15;
    const int tid = threadIdx.x;
    __shared__ float part[256];

    float vals[8];
    float run = 0.f;
#pragma unroll
    for (int j = 0; j < 8; ++j) {
        int t = tid * 8 + j;
        float x = g[(size_t)(b * 2048 + t) * 16 + h];
        float ls = fminf(x, 0.f) - log1pf(__expf(-fabsf(x)));
        run += ls * 1.4426950408889634f;
        vals[j] = run;
    }
    part[tid] = run;
    __syncthreads();
    for (int ofs = 1; ofs < 256; ofs <<= 1) {
        float add = (tid >= ofs) ? part[tid - ofs] : 0.f;
        __syncthreads();
        part[tid] += add;
        __syncthreads();
    }
    float excl = part[tid] - run;
#pragma unroll
    for (int j = 0; j < 8; ++j)
        lg[(size_t)bh * 2048 + tid * 8 + j] = excl + vals[j];
}

// ---------------------------------------------------------------------------
// Flash-style causal gated power attention (round-25, session best):
//  (256,3) [4 waves/EU clamps VGPR->spills], LPT dispatch, XCD-affinity map,
//  no-rescale linear accum, ones-MFMA row sums, K dbuf via gload_lds,
//  V->regs, factored gate exponential er[r]*ec[js].
// ---------------------------------------------------------------------------
__global__ __launch_bounds__(256, 3)
void attn_fwd(const unsigned short* __restrict__ Qh, const unsigned short* __restrict__ Ql,
              const unsigned short* __restrict__ Kh, const unsigned short* __restrict__ Kl,
              const unsigned short* __restrict__ Vtg, const float* __restrict__ lg,
              float* __restrict__ out)
{
    __shared__ __align__(16) unsigned short kh[2][64][64];
    __shared__ __align__(16) unsigned short kl[2][64][64];
    __shared__ __align__(16) unsigned short pl[4][16][64];

    const int bid = blockIdx.x;
    const int x8 = bid & 7;                 // assumed XCD id (round-robin)
    const int k  = bid >> 3;                // 0..127
    const int bh = x8 + 8 * (k & 3);        // 4 heads per XCD -> L2 affinity
    const int m  = k >> 2;                  // 0..31
    const int qi = 31 - m;                  // LPT: longest blocks dispatch first
    const int tid = threadIdx.x;
    const int w = tid >> 6, l = tid & 63;
    const int lr = l & 15, lq = l >> 4;
    const int xk = lr & 7;
    const int q0 = qi * 64;
    const int myrow0 = q0 + w * 16;

    const size_t qoff = ((size_t)bh * 2048 + myrow0 + lr) * 64;
    short8 qh8[2], ql8[2];
    qh8[0] = *(const short8*)&Qh[qoff + lq * 8];
    qh8[1] = *(const short8*)&Qh[qoff + 32 + lq * 8];
    ql8[0] = *(const short8*)&Ql[qoff + lq * 8];
    ql8[1] = *(const short8*)&Ql[qoff + 32 + lq * 8];

    float gq2[4];
#pragma unroll
    for (int r = 0; r < 4; ++r)
        gq2[r] = lg[(size_t)bh * 2048 + myrow0 + lq * 4 + r] - 3.0f;  // + log2(1/8)

    // row factors relative to row 0 (once per block; bounded [2^-25, 1])
    float er[4];
    er[0] = 1.f;
#pragma unroll
    for (int r = 1; r < 4; ++r) er[r] = exp2f(gq2[r] - gq2[0]);
    const float gq0 = gq2[0];

    f32x4 ls4 = (f32x4){0.f, 0.f, 0.f, 0.f};
    f32x4 o4[4];
#pragma unroll
    for (int i = 0; i < 4; ++i) o4[i] = (f32x4){0.f, 0.f, 0.f, 0.f};

    short8 ones8;
#pragma unroll
    for (int j = 0; j < 8; ++j) ones8[j] = (short)0x3F80;   // bf16 1.0

    const int srow = tid >> 3;          // 0..31  (+32 on 2nd pass)
    const int schunk = tid & 7;         // 16B chunk index

    const unsigned short* Kh_b = Kh + (size_t)bh * 2048 * 64;
    const unsigned short* Kl_b = Kl + (size_t)bh * 2048 * 64;
    const unsigned short* Vt_b = Vtg + (size_t)bh * 64 * 2048;

    auto STAGE = [&](int bsel, int kv0) {
#pragma unroll
        for (int p = 0; p < 2; ++p) {
            int r = srow + p * 32;
            int sc = (schunk ^ (r & 7)) * 8;     // inverse-swizzled source chunk
            gload_lds16(&Kh_b[(size_t)(kv0 + r) * 64 + sc], &kh[bsel][r][schunk * 8]);
            gload_lds16(&Kl_b[(size_t)(kv0 + r) * 64 + sc], &kl[bsel][r][schunk * 8]);
        }
    };

    STAGE(0, 0);
    __asm__ volatile("s_waitcnt vmcnt(0)" ::: "memory");
    __syncthreads();

    int cur = 0;
    for (int kv0 = 0; kv0 <= q0; kv0 += 64) {
        // V tile -> registers (issued first; L2-hot)
        uint4 vreg[8];
#pragma unroll
        for (int ds_ = 0; ds_ < 4; ++ds_) {
            const unsigned short* vp = &Vt_b[(size_t)(ds_ * 16 + lr) * 2048 + kv0 + lq * 8];
            vreg[ds_ * 2]     = *(const uint4*)vp;
            vreg[ds_ * 2 + 1] = *(const uint4*)(vp + 32);
        }
        if (kv0 + 64 <= q0) STAGE(cur ^ 1, kv0 + 64);   // overlap with compute

        // column gate factors (4 exp2/tile, replaces 16 exp2)
        float ec[4];
#pragma unroll
        for (int js = 0; js < 4; ++js)
            ec[js] = exp2f(gq0 - lg[(size_t)bh * 2048 + kv0 + js * 16 + lr]);

        // ---- S = Q K^T (split-bf16, 3 MFMA) ----
        f32x4 sa[4];
#pragma unroll
        for (int js = 0; js < 4; ++js) sa[js] = (f32x4){0.f, 0.f, 0.f, 0.f};
#pragma unroll
        for (int js = 0; js < 4; ++js)
#pragma unroll
            for (int ks = 0; ks < 2; ++ks) {
                short8 kb  = *(const short8*)&kh[cur][js * 16 + lr][((ks * 4 + lq) ^ xk) << 3];
                short8 kbl = *(const short8*)&kl[cur][js * 16 + lr][((ks * 4 + lq) ^ xk) << 3];
                sa[js] = mfma_bf16(qh8[ks], kb,  sa[js]);
                sa[js] = mfma_bf16(qh8[ks], kbl, sa[js]);
                sa[js] = mfma_bf16(ql8[ks], kb,  sa[js]);
            }

        // ---- linear scores w = (|S|+eps)^2 * er[r]*ec[js]; no normalization ----
        const bool diag = (kv0 == q0);
#pragma unroll
        for (int js = 0; js < 4; ++js) {
            float ecj = ec[js];
#pragma unroll
            for (int r = 0; r < 4; ++r) {
                float a = fabsf(sa[js][r]) + 1e-7f;
                float wv = a * a * (er[r] * ecj);
                if (diag && (js * 16 + lr > w * 16 + lq * 4 + r)) wv = 0.f;
                sa[js][r] = wv;
            }
        }

        // ---- P -> LDS (swizzled transpose, wave-local; truncating cast) ----
#pragma unroll
        for (int js = 0; js < 4; ++js)
#pragma unroll
            for (int r = 0; r < 4; ++r) {
                int prow = lq * 4 + r;
                int cch = (js * 2 + (lr >> 3)) ^ (prow & 7);
                pl[w][prow][(cch << 3) | (lr & 7)] = f2bf_trunc(sa[js][r]);
            }
        __asm__ volatile("s_waitcnt lgkmcnt(0)" ::: "memory");
        __builtin_amdgcn_sched_barrier(0);

        short8 pa0 = *(const short8*)&pl[w][lr][((0 + lq) ^ xk) << 3];
        short8 pa1 = *(const short8*)&pl[w][lr][((4 + lq) ^ xk) << 3];

        // row sums via ones-MFMA (every lane gets ls[r] for its rows)
        ls4 = mfma_bf16(pa0, ones8, ls4);
        ls4 = mfma_bf16(pa1, ones8, ls4);
#pragma unroll
        for (int ds_ = 0; ds_ < 4; ++ds_) {
            short8 vb0 = *(const short8*)&vreg[ds_ * 2];
            short8 vb1 = *(const short8*)&vreg[ds_ * 2 + 1];
            o4[ds_] = mfma_bf16(pa0, vb0, o4[ds_]);
            o4[ds_] = mfma_bf16(pa1, vb1, o4[ds_]);
        }

        __asm__ volatile("s_waitcnt vmcnt(0)" ::: "memory");
        __syncthreads();
        cur ^= 1;
    }

    const int b = bh >> 4, h = bh & 15;
#pragma unroll
    for (int ds_ = 0; ds_ < 4; ++ds_)
#pragma unroll
        for (int r = 0; r < 4; ++r) {
            int t = myrow0 + lq * 4 + r;
            out[(size_t)(b * 2048 + t) * 1024 + h * 64 + ds_ * 16 + lr] =
                o4[ds_][r] / ls4[r];
        }
}

// ---------------------------------------------------------------------------
extern "C" void kernel_launch(void* const* d_in, const int* in_sizes, int n_in,
                              void* d_out, int out_size, void* d_ws, size_t ws_size,
                              hipStream_t stream)
{
    const float* x = (const float*)d_in[0];   // [2][2048][1024]
    const float* W = (const float*)d_in[1];   // [3088][1024]
    float* out = (float*)d_out;               // [2][2048][1024]

    const size_t NX = 4194304;    // 2*2048*1024
    const size_t NW = 3162112;    // 3088*1024
    const size_t NQ = 4194304;    // 32*2048*64

    char* ws = (char*)d_ws;
    size_t off = 0;
    auto alloc = [&](size_t bytes) -> void* {
        void* p = ws + off;
        off += (bytes + 255) & ~(size_t)255;
        return p;
    };
    unsigned short* xh = (unsigned short*)alloc(NX * 2);
    unsigned short* xl = (unsigned short*)alloc(NX * 2);
    unsigned short* wh = (unsigned short*)alloc(NW * 2);
    unsigned short* wl = (unsigned short*)alloc(NW * 2);
    unsigned short* Qh = (unsigned short*)alloc(NQ * 2);
    unsigned short* Ql = (unsigned short*)alloc(NQ * 2);
    unsigned short* Kh = (unsigned short*)alloc(NQ * 2);
    unsigned short* Kl = (unsigned short*)alloc(NQ * 2);
    unsigned short* Vt = (unsigned short*)alloc(NQ * 2);
    float* g  = (float*)alloc(65536 * 4);
    float* lg = (float*)alloc(65536 * 4);
    if (off > ws_size) return;

    const int nx4 = (int)(NX / 4), nw4 = (int)(NW / 4);
    split_all<<<(nx4 + nw4 + 255) / 256, 256, 0, stream>>>(x, xh, xl, W, wh, wl, nx4, nw4);
    gemm_proj<<<768, 256, 0, stream>>>(xh, xl, wh, wl, Qh, Ql, Kh, Kl, Vt, g);
    gate_scan<<<32, 256, 0, stream>>>(g, lg);
    attn_fwd<<<1024, 256, 0, stream>>>(Qh, Ql, Kh, Kl, Vt, lg, out);
}